// Round 4
// baseline (194.529 us; speedup 1.0000x reference)
//
#include <hip/hip_runtime.h>
#include <hip/hip_cooperative_groups.h>

#define BB 8
#define TT 2048
#define DD 128
#define CH 32            // k-chunks for gram (fixed: grid = CH*BB = 256 blocks)
#define GS_STRIDE 136    // bf16 elems per LDS row of Gs (pad 128+8 -> uniform banks)
#define DS_STRIDE2 136   // bf16 elems per LDS row of Ds

typedef __attribute__((ext_vector_type(8))) short bf16x8;
typedef __attribute__((ext_vector_type(4))) float f32x4;

static __device__ __forceinline__ float bf2f(unsigned short u) {
    union { unsigned int i; float f; } v;
    v.i = ((unsigned int)u) << 16;
    return v.f;
}
static __device__ __forceinline__ unsigned short f2bf(float f) {
    union { float f; unsigned int i; } v; v.f = f;
    unsigned int x = v.i;
    return (unsigned short)((x + 0x7FFFu + ((x >> 16) & 1u)) >> 16);  // RNE
}

// ===========================================================================
// Fused cooperative kernel: gram partial -> grid sync -> reduce -> grid sync
// -> MFMA apply. 256 blocks x 256 threads (1 block/CU, co-resident).
// ===========================================================================
__global__ __launch_bounds__(256, 2) void fused_kernel(const float* __restrict__ enc,
                                                       const float* __restrict__ dec,
                                                       float* __restrict__ out,
                                                       unsigned short* __restrict__ P,
                                                       unsigned short* __restrict__ Gw) {
    // LDS: phase1 uses 32 KB fp32 tile; phase3 uses Gs (34816 B) + Ds (17408 B).
    __shared__ __align__(16) unsigned char smem[52224];
    const int blk   = blockIdx.x;
    const int t     = threadIdx.x;
    const int b     = blk >> 5;    // batch
    const int chunk = blk & 31;    // 64-row chunk within batch

    // ---------------- phase 1: partial Gram (VALU 8x8 outer product) -------
    {
        float* tile = (float*)smem;  // [64][128] fp32
        const float* src = enc + ((size_t)b * TT + (size_t)chunk * 64) * DD;
        #pragma unroll
        for (int i = 0; i < 8; ++i)
            ((float4*)tile)[i * 256 + t] = ((const float4*)src)[i * 256 + t];
        __syncthreads();

        const int r0 = (t >> 4) * 8;
        const int c0 = (t & 15) * 8;
        float acc[8][8];
        #pragma unroll
        for (int i = 0; i < 8; ++i)
            #pragma unroll
            for (int j = 0; j < 8; ++j) acc[i][j] = 0.0f;

        #pragma unroll 4
        for (int k = 0; k < 64; ++k) {
            const float4 ra = *(const float4*)&tile[k * DD + r0];
            const float4 rb = *(const float4*)&tile[k * DD + r0 + 4];
            const float4 ca = *(const float4*)&tile[k * DD + c0];
            const float4 cb = *(const float4*)&tile[k * DD + c0 + 4];
            const float er[8] = {ra.x, ra.y, ra.z, ra.w, rb.x, rb.y, rb.z, rb.w};
            const float ec[8] = {ca.x, ca.y, ca.z, ca.w, cb.x, cb.y, cb.z, cb.w};
            #pragma unroll
            for (int i = 0; i < 8; ++i)
                #pragma unroll
                for (int j = 0; j < 8; ++j)
                    acc[i][j] += er[i] * ec[j];
        }

        unsigned short* Pb = P + ((size_t)chunk * BB + b) * (DD * DD);
        #pragma unroll
        for (int i = 0; i < 8; ++i) {
            unsigned short row[8];
            #pragma unroll
            for (int j = 0; j < 8; ++j) row[j] = f2bf(acc[i][j]);
            *(uint4*)&Pb[(r0 + i) * DD + c0] = *(const uint4*)row;
        }
    }

    __threadfence();
    cooperative_groups::this_grid().sync();

    // ---------------- phase 2: reduce partials -> bf16 G --------------------
    if (t < 128) {
        const int g = blk * 128 + t;                 // ushort4 group, 0..32767
        const ushort4* Pu = (const ushort4*)P;
        const int stride = BB * DD * DD / 4;         // ushort4 per chunk
        float sx = 0.f, sy = 0.f, sz = 0.f, sw = 0.f;
        for (int c = 0; c < CH; ++c) {
            const ushort4 v = Pu[(size_t)c * stride + g];
            sx += bf2f(v.x); sy += bf2f(v.y); sz += bf2f(v.z); sw += bf2f(v.w);
        }
        ushort4 o; o.x = f2bf(sx); o.y = f2bf(sy); o.z = f2bf(sz); o.w = f2bf(sw);
        ((ushort4*)Gw)[g] = o;
    }

    __threadfence();
    cooperative_groups::this_grid().sync();

    // ---------------- phase 3: out[b] = dec[b] @ G[b] via MFMA --------------
    {
        unsigned short* Gs = (unsigned short*)smem;              // [128][136] bf16
        unsigned short* Ds = (unsigned short*)(smem + 34816);    // [64][136]  bf16

        // Stage G[b] (already bf16). G is symmetric, so row n of Gs supplies
        // the B-fragment for output columns n (B[k][n] = G[n][k]).
        const uint4* Gsrc = (const uint4*)(Gw + (size_t)b * DD * DD);
        #pragma unroll
        for (int i = 0; i < 8; ++i) {
            const int idx = i * 256 + t;   // 0..2047 (16B groups, 8 bf16 each)
            const int r   = idx >> 4;
            const int c8  = idx & 15;
            *(uint4*)&Gs[r * GS_STRIDE + c8 * 8] = Gsrc[idx];
        }
        // Stage dec tile (64 x 128), fp32 -> bf16.
        const float4* Dsrc = (const float4*)(dec + ((size_t)b * TT + (size_t)chunk * 64) * DD);
        #pragma unroll
        for (int i = 0; i < 8; ++i) {
            const int idx = i * 256 + t;   // 0..2047 float4
            const int row = idx >> 5;
            const int c4  = idx & 31;
            const float4 v = Dsrc[idx];
            ushort4 o; o.x = f2bf(v.x); o.y = f2bf(v.y); o.z = f2bf(v.z); o.w = f2bf(v.w);
            *(ushort4*)&Ds[row * DS_STRIDE2 + c4 * 4] = o;
        }
        __syncthreads();

        const int wave = t >> 6;
        const int lane = t & 63;
        const int quad = lane >> 4;
        const int ln   = lane & 15;
        const int qt   = wave * 16;        // q-tile row base (each wave: 16q x 128d)

        f32x4 acc[8];
        #pragma unroll
        for (int dt = 0; dt < 8; ++dt) acc[dt] = (f32x4){0.f, 0.f, 0.f, 0.f};

        #pragma unroll
        for (int ks = 0; ks < 4; ++ks) {
            // A-frag: A[m=ln][k=ks*32+quad*8+j] = dec row ln, consecutive k.
            const bf16x8 a = *(const bf16x8*)&Ds[(qt + ln) * DS_STRIDE2 + ks * 32 + quad * 8];
            #pragma unroll
            for (int dt = 0; dt < 8; ++dt) {
                // B-frag: B[k][n=ln] = G[k][dt*16+ln] = G[dt*16+ln][k] (symmetry).
                const bf16x8 bf = *(const bf16x8*)&Gs[(dt * 16 + ln) * GS_STRIDE + ks * 32 + quad * 8];
                acc[dt] = __builtin_amdgcn_mfma_f32_16x16x32_bf16(a, bf, acc[dt], 0, 0, 0);
            }
        }

        // Epilogue: C/D layout col=lane&15, row=quad*4+reg [m89-verified].
        float* ob = out + ((size_t)b * TT + (size_t)chunk * 64) * DD;
        #pragma unroll
        for (int dt = 0; dt < 8; ++dt) {
            const int d = dt * 16 + ln;
            #pragma unroll
            for (int r = 0; r < 4; ++r) {
                const int q = qt + quad * 4 + r;
                ob[q * DD + d] = acc[dt][r];
            }
        }
    }
}

// ===========================================================================
// Fallback path (R3's proven kernels, ushort bf16 partials) in case the
// cooperative launch is rejected at runtime.
// ===========================================================================
__global__ __launch_bounds__(256, 2) void gram_partial(const float* __restrict__ enc,
                                                       unsigned short* __restrict__ P) {
    const int b = blockIdx.y, chunk = blockIdx.x, t = threadIdx.x;
    __shared__ __align__(16) float tile[64 * DD];
    const float* src = enc + ((size_t)b * TT + (size_t)chunk * 64) * DD;
    #pragma unroll
    for (int i = 0; i < 8; ++i)
        ((float4*)tile)[i * 256 + t] = ((const float4*)src)[i * 256 + t];
    __syncthreads();
    const int r0 = (t >> 4) * 8, c0 = (t & 15) * 8;
    float acc[8][8];
    #pragma unroll
    for (int i = 0; i < 8; ++i)
        #pragma unroll
        for (int j = 0; j < 8; ++j) acc[i][j] = 0.0f;
    #pragma unroll 4
    for (int k = 0; k < 64; ++k) {
        const float4 ra = *(const float4*)&tile[k * DD + r0];
        const float4 rb = *(const float4*)&tile[k * DD + r0 + 4];
        const float4 ca = *(const float4*)&tile[k * DD + c0];
        const float4 cb = *(const float4*)&tile[k * DD + c0 + 4];
        const float er[8] = {ra.x, ra.y, ra.z, ra.w, rb.x, rb.y, rb.z, rb.w};
        const float ec[8] = {ca.x, ca.y, ca.z, ca.w, cb.x, cb.y, cb.z, cb.w};
        #pragma unroll
        for (int i = 0; i < 8; ++i)
            #pragma unroll
            for (int j = 0; j < 8; ++j) acc[i][j] += er[i] * ec[j];
    }
    unsigned short* Pb = P + ((size_t)chunk * BB + b) * (DD * DD);
    #pragma unroll
    for (int i = 0; i < 8; ++i) {
        unsigned short row[8];
        #pragma unroll
        for (int j = 0; j < 8; ++j) row[j] = f2bf(acc[i][j]);
        *(uint4*)&Pb[(r0 + i) * DD + c0] = *(const uint4*)row;
    }
}

__global__ __launch_bounds__(256) void gram_reduce(const unsigned short* __restrict__ P,
                                                   float* __restrict__ G) {
    const int g = blockIdx.x * 256 + threadIdx.x;
    const ushort4* Pu = (const ushort4*)P;
    const int stride = BB * DD * DD / 4;
    float4 s = make_float4(0.f, 0.f, 0.f, 0.f);
    for (int c = 0; c < CH; ++c) {
        const ushort4 v = Pu[(size_t)c * stride + g];
        s.x += bf2f(v.x); s.y += bf2f(v.y); s.z += bf2f(v.z); s.w += bf2f(v.w);
    }
    ((float4*)G)[g] = s;
}

#define DS_STRIDE 132
__global__ __launch_bounds__(256, 2) void apply_kernel(const float* __restrict__ dec,
                                                       const float* __restrict__ G,
                                                       float* __restrict__ out) {
    const int b = blockIdx.z, q0 = blockIdx.x * 64, d0b = blockIdx.y * 64, t = threadIdx.x;
    __shared__ __align__(16) float Gsh[DD * 64];
    __shared__ __align__(16) float Dsh[64 * DS_STRIDE];
    const float* Gb = G + b * DD * DD;
    #pragma unroll
    for (int i = 0; i < 8; ++i) {
        const int f4 = i * 256 + t, c = f4 >> 4, dl4 = f4 & 15;
        ((float4*)Gsh)[f4] = ((const float4*)(Gb + c * DD + d0b))[dl4];
    }
    const float* decb = dec + (size_t)b * TT * DD + (size_t)q0 * DD;
    #pragma unroll
    for (int i = 0; i < 8; ++i) {
        const int f4 = i * 256 + t, row = f4 >> 5, col4 = f4 & 31;
        ((float4*)Dsh)[row * (DS_STRIDE / 4) + col4] = ((const float4*)decb)[f4];
    }
    __syncthreads();
    const int dl = (t & 15) * 4, qb = (t >> 4) * 4;
    float4 acc[4];
    #pragma unroll
    for (int i = 0; i < 4; ++i) acc[i] = make_float4(0.f, 0.f, 0.f, 0.f);
    #pragma unroll 8
    for (int c = 0; c < DD; c += 4) {
        const float4 g0 = *(const float4*)&Gsh[(c + 0) * 64 + dl];
        const float4 g1 = *(const float4*)&Gsh[(c + 1) * 64 + dl];
        const float4 g2 = *(const float4*)&Gsh[(c + 2) * 64 + dl];
        const float4 g3 = *(const float4*)&Gsh[(c + 3) * 64 + dl];
        #pragma unroll
        for (int i = 0; i < 4; ++i) {
            const float4 dv = *(const float4*)&Dsh[(qb + i) * DS_STRIDE + c];
            acc[i].x += dv.x * g0.x + dv.y * g1.x + dv.z * g2.x + dv.w * g3.x;
            acc[i].y += dv.x * g0.y + dv.y * g1.y + dv.z * g2.y + dv.w * g3.y;
            acc[i].z += dv.x * g0.z + dv.y * g1.z + dv.z * g2.z + dv.w * g3.z;
            acc[i].w += dv.x * g0.w + dv.y * g1.w + dv.z * g2.w + dv.w * g3.w;
        }
    }
    float* ob = out + (size_t)b * TT * DD + (size_t)q0 * DD + d0b;
    #pragma unroll
    for (int i = 0; i < 4; ++i) *(float4*)&ob[(qb + i) * DD + dl] = acc[i];
}

extern "C" void kernel_launch(void* const* d_in, const int* in_sizes, int n_in,
                              void* d_out, int out_size, void* d_ws, size_t ws_size,
                              hipStream_t stream) {
    const float* enc = (const float*)d_in[0];  // (8,2048,128) fp32
    const float* dec = (const float*)d_in[1];  // (8,2048,128) fp32
    float* out = (float*)d_out;

    // ws layout: P bf16 partials (8 MB) | Gw bf16 (256 KB) | G32 fp32 (512 KB)
    unsigned short* P  = (unsigned short*)d_ws;
    unsigned short* Gw = (unsigned short*)((char*)d_ws + (size_t)CH * BB * DD * DD * 2);
    float*          G32 = (float*)((char*)d_ws + (size_t)CH * BB * DD * DD * 2
                                               + (size_t)BB * DD * DD * 2);

    void* args[5] = {(void*)&enc, (void*)&dec, (void*)&out, (void*)&P, (void*)&Gw};
    hipError_t e = hipLaunchCooperativeKernel((const void*)fused_kernel,
                                              dim3(256), dim3(256), args, 0, stream);
    if (e != hipSuccess) {
        // Deterministic fallback: proven 3-kernel path.
        gram_partial<<<dim3(CH, BB), 256, 0, stream>>>(enc, P);
        gram_reduce<<<BB * DD * DD / 4 / 256, 256, 0, stream>>>(P, G32);
        apply_kernel<<<dim3(32, 2, BB), 256, 0, stream>>>(dec, G32, out);
    }
}

// Round 5
// 77.171 us; speedup vs baseline: 2.5208x; 2.5208x over previous
//
#include <hip/hip_runtime.h>

#define BB 8
#define TT 2048
#define DD 128
#define CH 32              // k-chunks (64 rows each): grid = CH*BB = 256 blocks
#define GT_STRIDE 72       // bf16 elems per Gt row (64 + 8 pad)
#define DS_STRIDE 136      // bf16 elems per Ds row (128 + 8 pad)

typedef __attribute__((ext_vector_type(8))) short bf16x8;
typedef __attribute__((ext_vector_type(4))) float f32x4;
typedef unsigned short u16;

static __device__ __forceinline__ float bf2f(u16 u) {
    union { unsigned int i; float f; } v; v.i = ((unsigned int)u) << 16; return v.f;
}
static __device__ __forceinline__ u16 f2bf(float f) {
    union { float f; unsigned int i; } v; v.f = f;
    unsigned int x = v.i;
    return (u16)((x + 0x7FFFu + ((x >> 16) & 1u)) >> 16);  // RNE
}

// ===========================================================================
// Kernel 1: MFMA partial Gram. P[chunk][b] = enc_chunk^T @ enc_chunk (K=64).
// Both A (= enc^T) and B (= enc) fragments read ROWS of Gt = enc^T in LDS.
// Partials stored in MFMA C-layout: P[cb][tile=mt*8+nt][lane] = 4 bf16 (regs).
// Reduce is element-wise so this layout flows through to Gw untouched.
// ===========================================================================
__global__ __launch_bounds__(256, 1) void gram_mfma(const float* __restrict__ enc,
                                                    u16* __restrict__ P) {
    const int b     = blockIdx.y;
    const int chunk = blockIdx.x;
    const int t     = threadIdx.x;

    __shared__ __align__(16) u16 Gt[DD * GT_STRIDE];   // [d][k] = enc^T, 18 KB

    // Stage transpose: lane = d (coalesced 256B global reads), pack 4 k's -> b64.
    const float* src = enc + ((size_t)b * TT + (size_t)chunk * 64) * DD;
    const int d  = t & 127;
    const int kh = t >> 7;                 // 0..1
    #pragma unroll
    for (int a = 0; a < 8; ++a) {
        const int k4 = a * 2 + kh;         // 0..15
        u16 o[4];
        #pragma unroll
        for (int i = 0; i < 4; ++i)
            o[i] = f2bf(src[(k4 * 4 + i) * DD + d]);
        *(ushort4*)&Gt[d * GT_STRIDE + k4 * 4] = *(const ushort4*)o;
    }
    __syncthreads();

    const int wave = t >> 6, lane = t & 63, quad = lane >> 4, ln = lane & 15;

    // Wave w owns row-tiles mt = {2w, 2w+1} x all 8 col-tiles. K=64 -> 2 ksteps.
    bf16x8 afrag[2][2];
    #pragma unroll
    for (int mi = 0; mi < 2; ++mi)
        #pragma unroll
        for (int ks = 0; ks < 2; ++ks)
            afrag[mi][ks] = *(const bf16x8*)&Gt[((wave * 2 + mi) * 16 + ln) * GT_STRIDE
                                                + ks * 32 + quad * 8];
    f32x4 acc[2][8];
    #pragma unroll
    for (int mi = 0; mi < 2; ++mi)
        #pragma unroll
        for (int nt = 0; nt < 8; ++nt) acc[mi][nt] = (f32x4){0.f, 0.f, 0.f, 0.f};

    #pragma unroll
    for (int ks = 0; ks < 2; ++ks) {
        #pragma unroll
        for (int nt = 0; nt < 8; ++nt) {
            const bf16x8 bfrag = *(const bf16x8*)&Gt[(nt * 16 + ln) * GT_STRIDE
                                                     + ks * 32 + quad * 8];
            #pragma unroll
            for (int mi = 0; mi < 2; ++mi)
                acc[mi][nt] = __builtin_amdgcn_mfma_f32_16x16x32_bf16(
                    afrag[mi][ks], bfrag, acc[mi][nt], 0, 0, 0);
        }
    }

    // Epilogue: coalesced b64 stores in C-layout (tile, lane, 4 regs).
    u16* Pb = P + ((size_t)chunk * BB + b) * (DD * DD);
    #pragma unroll
    for (int mi = 0; mi < 2; ++mi) {
        #pragma unroll
        for (int nt = 0; nt < 8; ++nt) {
            u16 o[4];
            #pragma unroll
            for (int r = 0; r < 4; ++r) o[r] = f2bf(acc[mi][nt][r]);
            const int tile = (wave * 2 + mi) * 8 + nt;
            *(ushort4*)&Pb[tile * 256 + lane * 4] = *(const ushort4*)o;
        }
    }
}

// ===========================================================================
// Kernel 2: element-wise reduce over chunks: Gw[b] = sum_c P[c][b]  (bf16 out).
// Layout-agnostic. 128 blocks x 256 threads, one ushort4 group each.
// ===========================================================================
__global__ __launch_bounds__(256) void gram_reduce(const u16* __restrict__ P,
                                                   u16* __restrict__ Gw) {
    const int g = blockIdx.x * 256 + threadIdx.x;   // 0..32767
    const ushort4* Pu = (const ushort4*)P;
    const int stride = BB * DD * DD / 4;
    float sx = 0.f, sy = 0.f, sz = 0.f, sw = 0.f;
    for (int c = 0; c < CH; ++c) {
        const ushort4 v = Pu[(size_t)c * stride + g];
        sx += bf2f(v.x); sy += bf2f(v.y); sz += bf2f(v.z); sw += bf2f(v.w);
    }
    ushort4 o; o.x = f2bf(sx); o.y = f2bf(sy); o.z = f2bf(sz); o.w = f2bf(sw);
    ((ushort4*)Gw)[g] = o;
}

// ===========================================================================
// Kernel 3: out[b] = dec[b] @ G[b] via MFMA. Grid (32 q-chunks, 8 batches).
// Gs staged raw in tile-lane layout; B-frag (dt,ks,quad) = two b64 reads:
//   tile = (ks*2 + (quad>>1))*8 + dt, lanes (quad&1)*32+ln and +16, regs 0..3.
// Dec staging + epilogue are byte-identical to the R4 HW-verified phase 3.
// ===========================================================================
__global__ __launch_bounds__(256, 1) void apply_mfma(const float* __restrict__ dec,
                                                     const u16* __restrict__ Gw,
                                                     float* __restrict__ out) {
    const int b     = blockIdx.y;
    const int chunk = blockIdx.x;
    const int t     = threadIdx.x;

    __shared__ __align__(16) u16 Gs[DD * DD];          // 32 KB, raw tile-lane layout
    __shared__ __align__(16) u16 Ds[64 * DS_STRIDE];   // 17 KB

    const uint4* gsrc = (const uint4*)(Gw + (size_t)b * DD * DD);
    #pragma unroll
    for (int i = 0; i < 8; ++i)
        ((uint4*)Gs)[i * 256 + t] = gsrc[i * 256 + t];

    const float4* dsrc = (const float4*)(dec + ((size_t)b * TT + (size_t)chunk * 64) * DD);
    #pragma unroll
    for (int i = 0; i < 8; ++i) {
        const int idx = i * 256 + t;
        const int row = idx >> 5, c4 = idx & 31;
        const float4 v = dsrc[idx];
        u16 o[4] = {f2bf(v.x), f2bf(v.y), f2bf(v.z), f2bf(v.w)};
        *(ushort4*)&Ds[row * DS_STRIDE + c4 * 4] = *(const ushort4*)o;
    }
    __syncthreads();

    const int wave = t >> 6, lane = t & 63, quad = lane >> 4, ln = lane & 15;
    const int qt = wave * 16;

    f32x4 acc[8];
    #pragma unroll
    for (int dt = 0; dt < 8; ++dt) acc[dt] = (f32x4){0.f, 0.f, 0.f, 0.f};

    #pragma unroll
    for (int ks = 0; ks < 4; ++ks) {
        const bf16x8 a = *(const bf16x8*)&Ds[(qt + ln) * DS_STRIDE + ks * 32 + quad * 8];
        const int mtk = ks * 2 + (quad >> 1);
        const int lg  = (quad & 1) * 32 + ln;
        #pragma unroll
        for (int dt = 0; dt < 8; ++dt) {
            const int base = (mtk * 8 + dt) * 256;
            union { ushort4 h[2]; bf16x8 v; } bb;
            bb.h[0] = *(const ushort4*)&Gs[base + lg * 4];          // k%16 in [r0, r0+3]
            bb.h[1] = *(const ushort4*)&Gs[base + (lg + 16) * 4];   // k%16 in [r0+4, r0+7]
            acc[dt] = __builtin_amdgcn_mfma_f32_16x16x32_bf16(a, bb.v, acc[dt], 0, 0, 0);
        }
    }

    // Epilogue: C/D layout col=lane&15, row=quad*4+reg (HW-verified in R4).
    float* ob = out + ((size_t)b * TT + (size_t)chunk * 64) * DD;
    #pragma unroll
    for (int dt = 0; dt < 8; ++dt) {
        const int dcol = dt * 16 + ln;
        #pragma unroll
        for (int r = 0; r < 4; ++r) {
            const int q = qt + quad * 4 + r;
            ob[q * DD + dcol] = acc[dt][r];
        }
    }
}

extern "C" void kernel_launch(void* const* d_in, const int* in_sizes, int n_in,
                              void* d_out, int out_size, void* d_ws, size_t ws_size,
                              hipStream_t stream) {
    const float* enc = (const float*)d_in[0];  // (8,2048,128) fp32
    const float* dec = (const float*)d_in[1];  // (8,2048,128) fp32
    float* out = (float*)d_out;                // (8,2048,128) fp32

    // ws: P bf16 partials (8 MB) | Gw bf16 (256 KB)
    u16* P  = (u16*)d_ws;
    u16* Gw = (u16*)((char*)d_ws + (size_t)CH * BB * DD * DD * sizeof(u16));

    gram_mfma<<<dim3(CH, BB), 256, 0, stream>>>(enc, P);
    gram_reduce<<<BB * DD * DD / 4 / 256, 256, 0, stream>>>(P, Gw);
    apply_mfma<<<dim3(TT / 64, BB), 256, 0, stream>>>(dec, Gw, out);
}

// Round 6
// 76.659 us; speedup vs baseline: 2.5376x; 1.0067x over previous
//
#include <hip/hip_runtime.h>

#define BB 8
#define TT 2048
#define DD 128
#define CH 32              // k-chunks (64 rows each): grid = CH*BB = 256 blocks
#define GT_STRIDE 72       // bf16 elems per Gt row (64 + 8 pad)
#define DS_STRIDE 136      // bf16 elems per Ds row (128 + 8 pad)

typedef __attribute__((ext_vector_type(8))) short bf16x8;
typedef __attribute__((ext_vector_type(4))) float f32x4;
typedef unsigned short u16;

static __device__ __forceinline__ float bf2f(u16 u) {
    union { unsigned int i; float f; } v; v.i = ((unsigned int)u) << 16; return v.f;
}
static __device__ __forceinline__ u16 f2bf(float f) {
    union { float f; unsigned int i; } v; v.f = f;
    unsigned int x = v.i;
    return (u16)((x + 0x7FFFu + ((x >> 16) & 1u)) >> 16);  // RNE
}

// ===========================================================================
// Kernel 1: MFMA partial Gram. P[chunk][b] = enc_chunk^T @ enc_chunk (K=64).
// Both A (= enc^T) and B (= enc) fragments read ROWS of Gt = enc^T in LDS.
//
// P storage layout (NEW in R6): within each 16x16 tile, producing lane
// l=(q,ln) stores its 4 C-regs at elem offset  ln*16 + (q>>1)*8 + (q&1)*4.
// This makes the apply kernel's B-fragment (C-regs of lanes lg=(quad&1)*32+ln
// and lg+16) a SINGLE contiguous 16B group -> one ds_read_b128 (was 2x b64).
// Bank-balanced: 8 words/bank = the b128 floor. Reduce is element-wise, so
// the layout flows through Gw untouched.
// ===========================================================================
__global__ __launch_bounds__(256, 1) void gram_mfma(const float* __restrict__ enc,
                                                    u16* __restrict__ P) {
    const int b     = blockIdx.y;
    const int chunk = blockIdx.x;
    const int t     = threadIdx.x;

    __shared__ __align__(16) u16 Gt[DD * GT_STRIDE];   // [d][k] = enc^T, 18 KB

    // Stage transpose: lane = d (coalesced 256B/wave global reads), pack 4 k -> b64.
    const float* src = enc + ((size_t)b * TT + (size_t)chunk * 64) * DD;
    const int d  = t & 127;
    const int kh = t >> 7;                 // 0..1
    #pragma unroll
    for (int a = 0; a < 8; ++a) {
        const int k4 = a * 2 + kh;         // 0..15
        u16 o[4];
        #pragma unroll
        for (int i = 0; i < 4; ++i)
            o[i] = f2bf(src[(k4 * 4 + i) * DD + d]);
        *(ushort4*)&Gt[d * GT_STRIDE + k4 * 4] = *(const ushort4*)o;
    }
    __syncthreads();

    const int wave = t >> 6, lane = t & 63, quad = lane >> 4, ln = lane & 15;

    // Wave w owns row-tiles mt = {2w, 2w+1} x all 8 col-tiles. K=64 -> 2 ksteps.
    bf16x8 afrag[2][2];
    #pragma unroll
    for (int mi = 0; mi < 2; ++mi)
        #pragma unroll
        for (int ks = 0; ks < 2; ++ks)
            afrag[mi][ks] = *(const bf16x8*)&Gt[((wave * 2 + mi) * 16 + ln) * GT_STRIDE
                                                + ks * 32 + quad * 8];
    f32x4 acc[2][8];
    #pragma unroll
    for (int mi = 0; mi < 2; ++mi)
        #pragma unroll
        for (int nt = 0; nt < 8; ++nt) acc[mi][nt] = (f32x4){0.f, 0.f, 0.f, 0.f};

    #pragma unroll
    for (int ks = 0; ks < 2; ++ks) {
        #pragma unroll
        for (int nt = 0; nt < 8; ++nt) {
            const bf16x8 bfrag = *(const bf16x8*)&Gt[(nt * 16 + ln) * GT_STRIDE
                                                     + ks * 32 + quad * 8];
            #pragma unroll
            for (int mi = 0; mi < 2; ++mi)
                acc[mi][nt] = __builtin_amdgcn_mfma_f32_16x16x32_bf16(
                    afrag[mi][ks], bfrag, acc[mi][nt], 0, 0, 0);
        }
    }

    // Epilogue: b64 stores in the frag-keyed layout (512B contiguous per tile).
    u16* Pb = P + ((size_t)chunk * BB + b) * (DD * DD);
    const int off = ln * 16 + (quad >> 1) * 8 + (quad & 1) * 4;
    #pragma unroll
    for (int mi = 0; mi < 2; ++mi) {
        #pragma unroll
        for (int nt = 0; nt < 8; ++nt) {
            u16 o[4];
            #pragma unroll
            for (int r = 0; r < 4; ++r) o[r] = f2bf(acc[mi][nt][r]);
            const int tile = (wave * 2 + mi) * 8 + nt;
            *(ushort4*)&Pb[tile * 256 + off] = *(const ushort4*)o;
        }
    }
}

// ===========================================================================
// Kernel 2: element-wise reduce over chunks: Gw[b] = sum_c P[c][b]  (bf16 out).
// Layout-agnostic. 128 blocks x 256 threads, one ushort4 group each.
// ===========================================================================
__global__ __launch_bounds__(256) void gram_reduce(const u16* __restrict__ P,
                                                   u16* __restrict__ Gw) {
    const int g = blockIdx.x * 256 + threadIdx.x;   // 0..32767
    const ushort4* Pu = (const ushort4*)P;
    const int stride = BB * DD * DD / 4;
    float sx = 0.f, sy = 0.f, sz = 0.f, sw = 0.f;
    #pragma unroll 8
    for (int c = 0; c < CH; ++c) {
        const ushort4 v = Pu[(size_t)c * stride + g];
        sx += bf2f(v.x); sy += bf2f(v.y); sz += bf2f(v.z); sw += bf2f(v.w);
    }
    ushort4 o; o.x = f2bf(sx); o.y = f2bf(sy); o.z = f2bf(sz); o.w = f2bf(sw);
    ((ushort4*)Gw)[g] = o;
}

// ===========================================================================
// Kernel 3: out[b] = dec[b] @ G[b] via MFMA. Grid (32 q-chunks, 8 batches).
// Gs staged raw (frag-keyed layout); B-frag (mtk,dt,quad,ln) = ONE b128 at
//   tile = (ks*2 + (quad>>1))*8 + dt, elem tile*256 + ln*16 + (quad&1)*8.
// Dec staging + epilogue identical to the R5 HW-verified kernel.
// ===========================================================================
__global__ __launch_bounds__(256, 1) void apply_mfma(const float* __restrict__ dec,
                                                     const u16* __restrict__ Gw,
                                                     float* __restrict__ out) {
    const int b     = blockIdx.y;
    const int chunk = blockIdx.x;
    const int t     = threadIdx.x;

    __shared__ __align__(16) u16 Gs[DD * DD];          // 32 KB, raw frag-keyed layout
    __shared__ __align__(16) u16 Ds[64 * DS_STRIDE];   // 17 KB

    const uint4* gsrc = (const uint4*)(Gw + (size_t)b * DD * DD);
    #pragma unroll
    for (int i = 0; i < 8; ++i)
        ((uint4*)Gs)[i * 256 + t] = gsrc[i * 256 + t];

    const float4* dsrc = (const float4*)(dec + ((size_t)b * TT + (size_t)chunk * 64) * DD);
    #pragma unroll
    for (int i = 0; i < 8; ++i) {
        const int idx = i * 256 + t;
        const int row = idx >> 5, c4 = idx & 31;
        const float4 v = dsrc[idx];
        u16 o[4] = {f2bf(v.x), f2bf(v.y), f2bf(v.z), f2bf(v.w)};
        *(ushort4*)&Ds[row * DS_STRIDE + c4 * 4] = *(const ushort4*)o;
    }
    __syncthreads();

    const int wave = t >> 6, lane = t & 63, quad = lane >> 4, ln = lane & 15;
    const int qt = wave * 16;

    f32x4 acc[8];
    #pragma unroll
    for (int dt = 0; dt < 8; ++dt) acc[dt] = (f32x4){0.f, 0.f, 0.f, 0.f};

    #pragma unroll
    for (int ks = 0; ks < 4; ++ks) {
        const bf16x8 a = *(const bf16x8*)&Ds[(qt + ln) * DS_STRIDE + ks * 32 + quad * 8];
        const int mtk  = ks * 2 + (quad >> 1);
        const int boff = ln * 16 + (quad & 1) * 8;
        #pragma unroll
        for (int dt = 0; dt < 8; ++dt) {
            const bf16x8 bb = *(const bf16x8*)&Gs[(mtk * 8 + dt) * 256 + boff];
            acc[dt] = __builtin_amdgcn_mfma_f32_16x16x32_bf16(a, bb, acc[dt], 0, 0, 0);
        }
    }

    // Epilogue: C/D layout col=lane&15, row=quad*4+reg (HW-verified R4/R5).
    float* ob = out + ((size_t)b * TT + (size_t)chunk * 64) * DD;
    #pragma unroll
    for (int dt = 0; dt < 8; ++dt) {
        const int dcol = dt * 16 + ln;
        #pragma unroll
        for (int r = 0; r < 4; ++r) {
            const int q = qt + quad * 4 + r;
            ob[q * DD + dcol] = acc[dt][r];
        }
    }
}

extern "C" void kernel_launch(void* const* d_in, const int* in_sizes, int n_in,
                              void* d_out, int out_size, void* d_ws, size_t ws_size,
                              hipStream_t stream) {
    const float* enc = (const float*)d_in[0];  // (8,2048,128) fp32
    const float* dec = (const float*)d_in[1];  // (8,2048,128) fp32
    float* out = (float*)d_out;                // (8,2048,128) fp32

    // ws: P bf16 partials (8 MB) | Gw bf16 (256 KB)
    u16* P  = (u16*)d_ws;
    u16* Gw = (u16*)((char*)d_ws + (size_t)CH * BB * DD * DD * sizeof(u16));

    gram_mfma<<<dim3(CH, BB), 256, 0, stream>>>(enc, P);
    gram_reduce<<<BB * DD * DD / 4 / 256, 256, 0, stream>>>(P, Gw);
    apply_mfma<<<dim3(TT / 64, BB), 256, 0, stream>>>(dec, Gw, out);
}